// Round 1
// baseline (47.416 us; speedup 1.0000x reference)
//
#include <hip/hip_runtime.h>
#include <hip/hip_bf16.h>

// RGCN layer (R=8, B=4, N=1024, I=O=64, NB=4) on MI355X.
//
// Pipeline (all on `stream`, graph-capture safe):
//  prep_kernel : w_fullT per r in LDS; xT[rb][o][n] = (feat@w_full)^T bf16 via MFMA;
//                self-loop term -> comb[b][n][512+o]; zeroes deg.
//  agg_kernel  : comb[b][n][r*64+o] = sum_m adj[rb][m][n]*x[rb][m][o] via bf16 MFMA.
//                adj streamed 32 rows/step, transposed into LDS (XOR-swizzled),
//                xT panel resident in LDS. deg row-sums fused (LDS partials + atomicAdd).
//  out_kernel  : out[b][n][o] = relu(bias[o] + sum_{k=0..8} concat[b][n][9o+k]),
//                with agg entries divided by (deg+eps).

#define NN 1024
#define EPSK 1e-7f

typedef __bf16 bf16x8 __attribute__((ext_vector_type(8)));
typedef float f32x4 __attribute__((ext_vector_type(4)));

__device__ __forceinline__ unsigned short f2bf(float f) {
  union { float f; unsigned int u; } v; v.f = f;
  unsigned int r = (v.u + 0x7FFFu + ((v.u >> 16) & 1u)) >> 16;
  return (unsigned short)r;
}

// ---------------------------------------------------------------------------
// prep: 288 blocks x 256 thr. bid<256: (r,b,chunk) -> xT. bid>=256: self term.
// ---------------------------------------------------------------------------
__global__ __launch_bounds__(256) void prep_kernel(
    const float* __restrict__ feat,    // [4,1024,64]
    const float* __restrict__ weight,  // [4,64,64]
    const float* __restrict__ Wo,      // [64,64]
    const float* __restrict__ wcmp,    // [8,4]
    unsigned short* __restrict__ xT,   // [32][64][1024] bf16
    float* __restrict__ comb,          // [4][1024][576] f32
    float* __restrict__ deg)           // [32][1024] f32
{
  __shared__ __align__(16) unsigned short featL[128 * 72];  // [n][i] bf16, stride 72
  __shared__ __align__(16) unsigned short wT[64 * 72];      // [o][i] bf16, stride 72

  const int bid = blockIdx.x;
  const int t = threadIdx.x;

  const bool isSelf = bid >= 256;
  int r, b, chunk;
  if (!isSelf) { r = bid >> 5; b = (bid >> 3) & 3; chunk = bid & 7; }
  else { const int s = bid - 256; b = s >> 3; chunk = s & 7; r = 8; }
  const int n0 = chunk << 7;

  // zero deg (completes before agg_kernel by stream ordering)
  if (bid < 32) {
    for (int k = t; k < NN; k += 256) deg[bid * NN + k] = 0.0f;
  }

  // stage features chunk [128 n][64 i] f32 -> bf16 LDS
  const float* fsrc = feat + ((size_t)(b * NN + n0)) * 64;
  #pragma unroll
  for (int p = 0; p < 8; ++p) {
    const int idx = p * 256 + t;
    const int row = idx >> 4, c4 = idx & 15;
    const float4 v = *reinterpret_cast<const float4*>(fsrc + row * 64 + c4 * 4);
    ushort4 u;
    u.x = f2bf(v.x); u.y = f2bf(v.y); u.z = f2bf(v.z); u.w = f2bf(v.w);
    *reinterpret_cast<ushort4*>(&featL[row * 72 + c4 * 4]) = u;
  }

  // wT[o][i] = (r<8) ? sum_nb wcmp[r][nb]*weight[nb][i][o] : Wo[i][o]
  if (!isSelf) {
    const float wc0 = wcmp[r * 4 + 0], wc1 = wcmp[r * 4 + 1];
    const float wc2 = wcmp[r * 4 + 2], wc3 = wcmp[r * 4 + 3];
    #pragma unroll
    for (int j = 0; j < 16; ++j) {
      const int idx = j * 256 + t;
      const int o = idx & 63, i = idx >> 6;
      const float a = wc0 * weight[(0 * 64 + i) * 64 + o] + wc1 * weight[(1 * 64 + i) * 64 + o] +
                      wc2 * weight[(2 * 64 + i) * 64 + o] + wc3 * weight[(3 * 64 + i) * 64 + o];
      wT[o * 72 + i] = f2bf(a);
    }
  } else {
    #pragma unroll
    for (int j = 0; j < 16; ++j) {
      const int idx = j * 256 + t;
      const int o = idx & 63, i = idx >> 6;
      wT[o * 72 + i] = f2bf(Wo[i * 64 + o]);
    }
  }
  __syncthreads();

  const int w = t >> 6, lane = t & 63;
  const int li = lane & 15, lg = lane >> 4;
  const f32x4 zero = {0.f, 0.f, 0.f, 0.f};

  if (!isSelf) {
    // D[o][n] = sum_i wT[o][i]*feat[n][i]  (A=wT rows o, B=featL "cols" n)
    f32x4 acc[8];
    #pragma unroll
    for (int j = 0; j < 8; ++j) acc[j] = zero;
    #pragma unroll
    for (int ks = 0; ks < 2; ++ks) {
      const int kof = ks * 32 + lg * 8;
      const bf16x8 af = __builtin_bit_cast(bf16x8,
          *reinterpret_cast<const uint4*>(&wT[(w * 16 + li) * 72 + kof]));
      #pragma unroll
      for (int j = 0; j < 8; ++j) {
        const bf16x8 bfv = __builtin_bit_cast(bf16x8,
            *reinterpret_cast<const uint4*>(&featL[(j * 16 + li) * 72 + kof]));
        acc[j] = __builtin_amdgcn_mfma_f32_16x16x32_bf16(af, bfv, acc[j], 0, 0, 0);
      }
    }
    unsigned short* dst = xT + ((size_t)((r * 4 + b) * 64)) * NN;
    #pragma unroll
    for (int j = 0; j < 8; ++j) {
      #pragma unroll
      for (int qq = 0; qq < 4; ++qq) {
        const int o = w * 16 + lg * 4 + qq;
        const int n = n0 + j * 16 + li;
        dst[o * NN + n] = f2bf(acc[j][qq]);
      }
    }
  } else {
    // D[n][o] = sum_i feat[n][i]*Wo[i][o]
    f32x4 acc[2][4];
    #pragma unroll
    for (int a = 0; a < 2; ++a)
      #pragma unroll
      for (int j = 0; j < 4; ++j) acc[a][j] = zero;
    #pragma unroll
    for (int ks = 0; ks < 2; ++ks) {
      const int kof = ks * 32 + lg * 8;
      const bf16x8 a0 = __builtin_bit_cast(bf16x8,
          *reinterpret_cast<const uint4*>(&featL[(w * 32 + li) * 72 + kof]));
      const bf16x8 a1 = __builtin_bit_cast(bf16x8,
          *reinterpret_cast<const uint4*>(&featL[(w * 32 + 16 + li) * 72 + kof]));
      #pragma unroll
      for (int ot = 0; ot < 4; ++ot) {
        const bf16x8 bv = __builtin_bit_cast(bf16x8,
            *reinterpret_cast<const uint4*>(&wT[(ot * 16 + li) * 72 + kof]));
        acc[0][ot] = __builtin_amdgcn_mfma_f32_16x16x32_bf16(a0, bv, acc[0][ot], 0, 0, 0);
        acc[1][ot] = __builtin_amdgcn_mfma_f32_16x16x32_bf16(a1, bv, acc[1][ot], 0, 0, 0);
      }
    }
    float* dst = comb + (size_t)b * NN * 576;
    #pragma unroll
    for (int nt = 0; nt < 2; ++nt)
      #pragma unroll
      for (int ot = 0; ot < 4; ++ot)
        #pragma unroll
        for (int qq = 0; qq < 4; ++qq) {
          const int n = n0 + w * 32 + nt * 16 + lg * 4 + qq;
          const int o = ot * 16 + li;
          dst[(size_t)n * 576 + 512 + o] = acc[nt][ot][qq];
        }
  }
}

// ---------------------------------------------------------------------------
// agg: 256 blocks x 512 thr (8 waves, 1 block/CU). Block = (rb, 128 columns).
// out[n][o] = sum_m adj[m][n]*x[m][o]; deg[m] += row-sums over this column panel.
// ---------------------------------------------------------------------------
__global__ __launch_bounds__(512) void agg_kernel(
    const int* __restrict__ adj,            // [32][1024][1024]
    const unsigned short* __restrict__ xT,  // [32][64][1024] bf16
    float* __restrict__ comb,               // [4][1024][576]
    float* __restrict__ deg)                // [32][1024]
{
  __shared__ __align__(16) unsigned short xlds[64 * 1032];    // [o][m] bf16, stride 1032
  __shared__ __align__(16) unsigned short adjT[2][128 * 40];  // [n][m^swz] bf16, stride 40
  __shared__ __align__(16) float degP[2][32][36];             // per-step deg partials

  const int bid = blockIdx.x;
  const int rb = bid >> 3, r = rb >> 2, b = rb & 3;
  const int ncol0 = (bid & 7) << 7;
  const int t = threadIdx.x;

  // load xT panel (128 KB) into LDS once
  const unsigned short* xs = xT + ((size_t)rb << 16);
  #pragma unroll
  for (int it = 0; it < 16; ++it) {
    const int idx = t + (it << 9);
    const int row = idx >> 7, seg = idx & 127;
    const uint4 v = *reinterpret_cast<const uint4*>(xs + row * NN + seg * 8);
    *reinterpret_cast<uint4*>(&xlds[row * 1032 + seg * 8]) = v;
  }

  // staging assignment: thread=(q,mp): rows m=2mp,2mp+1, column-quad 4q
  const int q = t & 31, mp = t >> 5;
  const int* asrc = adj + ((size_t)rb << 20) + ncol0 + (q << 2);
  int4 p0 = *reinterpret_cast<const int4*>(asrc + ((size_t)(2 * mp) << 10));
  int4 p1 = *reinterpret_cast<const int4*>(asrc + ((size_t)(2 * mp + 1) << 10));

  const int w = t >> 6, lane = t & 63;
  const int li = lane & 15, lg = lane >> 4;
  const int arow = w * 16 + li;                               // A-frag row (n within tile)
  const int aoffs = arow * 40 + ((lg * 8) ^ ((w & 3) << 3));  // swizzled m-block
  const int boffs = li * 1032 + lg * 8;                       // xlds: +ot*16*1032 + m0

  f32x4 acc[4];
  const f32x4 zero = {0.f, 0.f, 0.f, 0.f};
  #pragma unroll
  for (int j = 0; j < 4; ++j) acc[j] = zero;

  __syncthreads();  // xlds ready

  for (int s = 0; s < 32; ++s) {
    unsigned short* at = adjT[s & 1];
    const int a0[4] = {p0.x, p0.y, p0.z, p0.w};
    const int a1[4] = {p1.x, p1.y, p1.z, p1.w};
    // transpose-write tile s (0/1 -> bf16 1.0/0.0), XOR-swizzle on m to spread banks
    #pragma unroll
    for (int j = 0; j < 4; ++j) {
      const int row = (q << 2) + j;
      const int col = (mp << 1) ^ (((row >> 4) & 3) << 3);
      const unsigned int packed = (a0[j] ? 0x3F80u : 0u) | (a1[j] ? 0x3F800000u : 0u);
      *reinterpret_cast<unsigned int*>(&at[row * 40 + col]) = packed;
    }
    degP[s & 1][2 * mp][q]     = (float)(a0[0] + a0[1] + a0[2] + a0[3]);
    degP[s & 1][2 * mp + 1][q] = (float)(a1[0] + a1[1] + a1[2] + a1[3]);

    // prefetch tile s+1
    if (s < 31) {
      const int* nsrc = asrc + ((size_t)((s + 1) * 32) << 10);
      p0 = *reinterpret_cast<const int4*>(nsrc + ((size_t)(2 * mp) << 10));
      p1 = *reinterpret_cast<const int4*>(nsrc + ((size_t)(2 * mp + 1) << 10));
    }
    __syncthreads();

    // deg partial reduce (wave 0, lanes 0..31) — exact integer sums in f32
    if (t < 32) {
      float sum = 0.f;
      #pragma unroll
      for (int k4 = 0; k4 < 8; ++k4) {
        const float4 vv = *reinterpret_cast<const float4*>(&degP[s & 1][t][k4 * 4]);
        sum += vv.x + vv.y + vv.z + vv.w;
      }
      atomicAdd(&deg[rb * NN + s * 32 + t], sum);
    }

    // MFMA: D[n][o] += A^T[n][m-step] * x[m-step][o]
    const bf16x8 af = __builtin_bit_cast(bf16x8,
        *reinterpret_cast<const uint4*>(&at[aoffs]));
    const int m0 = s * 32;
    #pragma unroll
    for (int ot = 0; ot < 4; ++ot) {
      const bf16x8 bv = __builtin_bit_cast(bf16x8,
          *reinterpret_cast<const uint4*>(&xlds[boffs + ot * 16 * 1032 + m0]));
      acc[ot] = __builtin_amdgcn_mfma_f32_16x16x32_bf16(af, bv, acc[ot], 0, 0, 0);
    }
  }

  // write un-normalized agg into comb[b][n][r*64+o]
  float* dst = comb + ((size_t)(b * NN + ncol0)) * 576 + r * 64;
  #pragma unroll
  for (int ot = 0; ot < 4; ++ot)
    #pragma unroll
    for (int qq = 0; qq < 4; ++qq) {
      const int n = w * 16 + lg * 4 + qq;
      const int o = ot * 16 + li;
      dst[(size_t)n * 576 + o] = acc[ot][qq];
    }
}

// ---------------------------------------------------------------------------
// epilogue: faithful regroup out[b,n,o] = relu(bias + sum_k concat[b,n,9o+k])
// ---------------------------------------------------------------------------
__global__ __launch_bounds__(256) void out_kernel(
    const float* __restrict__ comb, const float* __restrict__ deg,
    const float* __restrict__ bias, float* __restrict__ out)
{
  const int gid = blockIdx.x * 256 + threadIdx.x;
  const int o = gid & 63;
  const int n = (gid >> 6) & 1023;
  const int b = gid >> 16;
  const float* cp = comb + ((size_t)(b * NN + n)) * 576;
  float sum = bias[o];
  const int j0 = 9 * o;
  #pragma unroll
  for (int k = 0; k < 9; ++k) {
    const int j = j0 + k;
    float v = cp[j];
    if (j < 512) {
      v = v / (deg[((j >> 6) * 4 + b) * NN + n] + EPSK);
    }
    sum += v;
  }
  out[gid] = fmaxf(sum, 0.0f);
}

extern "C" void kernel_launch(void* const* d_in, const int* in_sizes, int n_in,
                              void* d_out, int out_size, void* d_ws, size_t ws_size,
                              hipStream_t stream) {
  const float* feat   = (const float*)d_in[0];
  const int*   adj    = (const int*)d_in[1];
  const float* weight = (const float*)d_in[2];
  const float* Wo     = (const float*)d_in[3];
  const float* wcmp   = (const float*)d_in[4];
  const float* bias   = (const float*)d_in[5];
  float* out = (float*)d_out;

  // ws layout: xT (4 MiB bf16) | comb (9 MiB f32) | deg (128 KiB f32) = ~13.8 MB
  char* ws = (char*)d_ws;
  unsigned short* xT = (unsigned short*)(ws);
  float* comb = (float*)(ws + 4194304u);
  float* deg  = (float*)(ws + 4194304u + 9437184u);

  prep_kernel<<<dim3(288), dim3(256), 0, stream>>>(feat, weight, Wo, wcmp, xT, comb, deg);
  agg_kernel<<<dim3(256), dim3(512), 0, stream>>>(adj, xT, comb, deg);
  out_kernel<<<dim3(1024), dim3(256), 0, stream>>>(comb, deg, bias, out);
}

// Round 2
// 36.081 us; speedup vs baseline: 1.3141x; 1.3141x over previous
//
#include <hip/hip_runtime.h>
#include <hip/hip_bf16.h>

// RGCN layer (R=8, B=4, N=1024, I=O=64, NB=4) on MI355X.
//
// Regroup folding: out[b,n,o] = relu(bias[o] + sum_{j=9o..9o+8} concat[b,n,j]).
// Channel j=64r+c of relation r lands at o=(64r+c)/9, i.e. slot s=(r+c)/9 in
// [0,8). Fold w_full columns -> w~[i][s] (8 slots/relation, padded to 16), so
// agg computes only 8 channels per relation. aggX[b][n][72] holds slot s of
// relation r at index 8r+s = o+r (self at 64+s = o+8).
//
//  prep_kernel : w~ fold in LDS; x~T[rb][16][1024] bf16 via MFMA; self-loop
//                folded term -> aggX[b][n][64+s]; zeroes deg.
//  agg_kernel  : aggX[b][n][8r+s] = sum_m adj[rb][m][n]*x~[rb][m][s] via MFMA.
//                adj streamed 32 rows/step, transposed+swizzled into LDS.
//                Raw s_barrier + lgkm fence; depth-4 reg prefetch keeps adj
//                loads in flight across barriers (no vmcnt(0) drain).
//  out_kernel  : out[o] = relu(bias[o] + f(r1) + [r2!=r1]f(r2)),
//                r1=(9o)>>6, r2=(9o+8)>>6, f(r)=aggX[o+r]/(deg+eps) (r<8).

#define NN 1024
#define EPSK 1e-7f

typedef __bf16 bf16x8 __attribute__((ext_vector_type(8)));
typedef float f32x4 __attribute__((ext_vector_type(4)));

__device__ __forceinline__ unsigned short f2bf(float f) {
  union { float f; unsigned int u; } v; v.f = f;
  return (unsigned short)((v.u + 0x7FFFu + ((v.u >> 16) & 1u)) >> 16);
}

// ---------------------------------------------------------------------------
// prep: 288 blocks x 256 thr. bid<256: (r,b,chunk) -> x~T. bid>=256: self.
// ---------------------------------------------------------------------------
__global__ __launch_bounds__(256) void prep_kernel(
    const float* __restrict__ feat,    // [4,1024,64]
    const float* __restrict__ weight,  // [4,64,64]
    const float* __restrict__ Wo,      // [64,64]
    const float* __restrict__ wcmp,    // [8,4]
    unsigned short* __restrict__ xT,   // [32][16][1024] bf16 (slots 8..15 = 0)
    float* __restrict__ aggX,          // [4][1024][72] f32
    float* __restrict__ deg)           // [32][1024] f32
{
  __shared__ __align__(16) unsigned short featL[128 * 72];  // [n][i] bf16
  __shared__ __align__(16) float wTf[64 * 65];              // [c][i] f32
  __shared__ __align__(16) unsigned short wfold[16 * 72];   // [s][i] bf16

  const int bid = blockIdx.x;
  const int t = threadIdx.x;
  const bool isSelf = bid >= 256;
  int r, b, chunk;
  if (!isSelf) { r = bid >> 5; b = (bid >> 3) & 3; chunk = bid & 7; }
  else { const int s2 = bid - 256; b = s2 >> 3; chunk = s2 & 7; r = 8; }
  const int n0 = chunk << 7;

  // zero deg (stream-ordered before agg)
  if (bid < 32) {
    for (int k = t; k < NN; k += 256) deg[bid * NN + k] = 0.0f;
  }

  // stage features chunk [128 n][64 i] -> bf16 LDS
  const float* fsrc = feat + ((size_t)(b * NN + n0)) * 64;
  #pragma unroll
  for (int p = 0; p < 8; ++p) {
    const int idx = p * 256 + t;
    const int row = idx >> 4, c4 = idx & 15;
    const float4 v = *reinterpret_cast<const float4*>(fsrc + row * 64 + c4 * 4);
    ushort4 u;
    u.x = f2bf(v.x); u.y = f2bf(v.y); u.z = f2bf(v.z); u.w = f2bf(v.w);
    *reinterpret_cast<ushort4*>(&featL[row * 72 + c4 * 4]) = u;
  }

  // wTf[c][i] = w_full[i][c] (f32, unrounded)
  if (!isSelf) {
    const float wc0 = wcmp[r * 4 + 0], wc1 = wcmp[r * 4 + 1];
    const float wc2 = wcmp[r * 4 + 2], wc3 = wcmp[r * 4 + 3];
    #pragma unroll
    for (int jj = 0; jj < 16; ++jj) {
      const int e = jj * 256 + t;
      const int i = e >> 6, c = e & 63;
      wTf[c * 65 + i] = wc0 * weight[i * 64 + c] + wc1 * weight[4096 + i * 64 + c] +
                        wc2 * weight[8192 + i * 64 + c] + wc3 * weight[12288 + i * 64 + c];
    }
  } else {
    #pragma unroll
    for (int jj = 0; jj < 16; ++jj) {
      const int e = jj * 256 + t;
      const int i = e >> 6, c = e & 63;
      wTf[c * 65 + i] = Wo[i * 64 + c];
    }
  }
  __syncthreads();

  // fold: wfold[s][i] = sum_{c : (r+c)/9 == s} wTf[c][i]; rows 8..15 zero
  #pragma unroll
  for (int jj = 0; jj < 4; ++jj) {
    const int e = jj * 256 + t;
    const int s = e >> 6, i = e & 63;
    float sum = 0.f;
    if (s < 8) {
      const int c0 = 9 * s - r;
      const int clo = c0 < 0 ? 0 : c0;
      const int chi = (c0 + 8 > 63) ? 63 : c0 + 8;
      for (int c = clo; c <= chi; ++c) sum += wTf[c * 65 + i];
    }
    wfold[s * 72 + i] = f2bf(sum);
  }
  __syncthreads();

  // MFMA: D[slot][n] = sum_i wfold[slot][i] * featL[n][i]; 4 waves x 2 n-tiles
  const int w = t >> 6, lane = t & 63;
  const int li = lane & 15, lg = lane >> 4;
  f32x4 acc0 = {0.f, 0.f, 0.f, 0.f}, acc1 = {0.f, 0.f, 0.f, 0.f};
  #pragma unroll
  for (int ks = 0; ks < 2; ++ks) {
    const int kof = ks * 32 + lg * 8;
    const bf16x8 af = __builtin_bit_cast(bf16x8,
        *reinterpret_cast<const uint4*>(&wfold[li * 72 + kof]));
    const bf16x8 b0 = __builtin_bit_cast(bf16x8,
        *reinterpret_cast<const uint4*>(&featL[((2 * w + 0) * 16 + li) * 72 + kof]));
    const bf16x8 b1 = __builtin_bit_cast(bf16x8,
        *reinterpret_cast<const uint4*>(&featL[((2 * w + 1) * 16 + li) * 72 + kof]));
    acc0 = __builtin_amdgcn_mfma_f32_16x16x32_bf16(af, b0, acc0, 0, 0, 0);
    acc1 = __builtin_amdgcn_mfma_f32_16x16x32_bf16(af, b1, acc1, 0, 0, 0);
  }
  // lane holds D[slot = lg*4+qq][n = tile*16 + li]
  if (!isSelf) {
    unsigned short* dst = xT + ((size_t)(r * 4 + b)) * (16 * NN);
    #pragma unroll
    for (int qq = 0; qq < 4; ++qq) {
      const int s = lg * 4 + qq;
      dst[s * NN + n0 + (2 * w + 0) * 16 + li] = f2bf(acc0[qq]);
      dst[s * NN + n0 + (2 * w + 1) * 16 + li] = f2bf(acc1[qq]);
    }
  } else {
    #pragma unroll
    for (int qq = 0; qq < 4; ++qq) {
      const int s = lg * 4 + qq;
      if (s < 8) {
        aggX[((size_t)(b * NN + n0 + (2 * w + 0) * 16 + li)) * 72 + 64 + s] = acc0[qq];
        aggX[((size_t)(b * NN + n0 + (2 * w + 1) * 16 + li)) * 72 + 64 + s] = acc1[qq];
      }
    }
  }
}

// ---------------------------------------------------------------------------
// agg: 512 blocks x 256 thr (4 waves, 2 blocks/CU). Block = (rb, 64 columns).
// Raw-barrier pipeline, depth-4 adj prefetch in registers (static indices).
// ---------------------------------------------------------------------------
__global__ __launch_bounds__(256) void agg_kernel(
    const int* __restrict__ adj,            // [32][1024][1024]
    const unsigned short* __restrict__ xT,  // [32][16][1024] bf16
    float* __restrict__ aggX,               // [4][1024][72]
    float* __restrict__ deg)                // [32][1024]
{
  __shared__ __align__(16) unsigned short xlds[16 * 1032];   // [slot][m] bf16
  __shared__ __align__(16) unsigned short adjT[2][64 * 40];  // [n][m^swz] bf16
  __shared__ __align__(16) float degP[2][32][20];            // deg partials

  const int bid = blockIdx.x;
  const int rb = bid >> 4, r = rb >> 2, b = rb & 3;
  const int ncol0 = (bid & 15) << 6;
  const int t = threadIdx.x;
  const int q = t & 15, mp = t >> 4;  // column-quad, row-pair

  const int* asrc = adj + (((size_t)rb) << 20) + ncol0 + (q << 2);

  // issue prefetch for steps 0..3 first (oldest in vmcnt queue)
  int4 pA[4], pB[4];
  #pragma unroll
  for (int u = 0; u < 4; ++u) {
    pA[u] = *reinterpret_cast<const int4*>(asrc + ((size_t)(u * 32 + 2 * mp) << 10));
    pB[u] = *reinterpret_cast<const int4*>(asrc + ((size_t)(u * 32 + 2 * mp + 1) << 10));
  }

  // stage x~ panel (32 KB) into LDS
  const unsigned short* xs = xT + (((size_t)rb) << 14);
  #pragma unroll
  for (int it = 0; it < 8; ++it) {
    const int idx = t + (it << 8);
    const int row = idx >> 7, seg = idx & 127;
    *reinterpret_cast<uint4*>(&xlds[row * 1032 + seg * 8]) =
        *reinterpret_cast<const uint4*>(xs + row * NN + seg * 8);
  }

  const int w = t >> 6, lane = t & 63;
  const int li = lane & 15, lg = lane >> 4;
  const int arow = w * 16 + li;
  const int aoffs = arow * 40 + ((lg * 8) ^ ((w & 3) << 3));
  const int boffs = li * 1032 + lg * 8;

  f32x4 acc = {0.f, 0.f, 0.f, 0.f};

  for (int tt = 0; tt < 8; ++tt) {
    #pragma unroll
    for (int u = 0; u < 4; ++u) {
      const int s = tt * 4 + u;
      // transpose-write tile s from regs (compiler inserts counted vmcnt wait)
      const int a0[4] = {pA[u].x, pA[u].y, pA[u].z, pA[u].w};
      const int a1[4] = {pB[u].x, pB[u].y, pB[u].z, pB[u].w};
      #pragma unroll
      for (int j = 0; j < 4; ++j) {
        const int row = (q << 2) + j;
        const int col = (mp << 1) ^ (((row >> 4) & 3) << 3);
        const unsigned int packed = (a0[j] ? 0x3F80u : 0u) | (a1[j] ? 0x3F800000u : 0u);
        *reinterpret_cast<unsigned int*>(&adjT[u & 1][row * 40 + col]) = packed;
      }
      degP[u & 1][2 * mp][q]     = (float)(a0[0] + a0[1] + a0[2] + a0[3]);
      degP[u & 1][2 * mp + 1][q] = (float)(a1[0] + a1[1] + a1[2] + a1[3]);

      // issue loads for step s+4 into the freed regs (stay in flight across barrier)
      if (s < 28) {
        const int* nsrc = asrc + ((size_t)((s + 4) * 32) << 10);
        pA[u] = *reinterpret_cast<const int4*>(nsrc + ((size_t)(2 * mp) << 10));
        pB[u] = *reinterpret_cast<const int4*>(nsrc + ((size_t)(2 * mp + 1) << 10));
      }

      // LDS writes visible, then raw barrier (no vmcnt drain)
      asm volatile("s_waitcnt lgkmcnt(0)" ::: "memory");
      __builtin_amdgcn_s_barrier();

      // deg partial reduce (wave 0) — exact small integers in f32
      if (t < 32) {
        float sum = 0.f;
        #pragma unroll
        for (int k4 = 0; k4 < 4; ++k4) {
          const float4 vv = *reinterpret_cast<const float4*>(&degP[u & 1][t][k4 * 4]);
          sum += vv.x + vv.y + vv.z + vv.w;
        }
        atomicAdd(&deg[rb * NN + s * 32 + t], sum);
      }

      // MFMA: D[n][slot] += adjT[n][m-step] * x~[m-step][slot]
      const bf16x8 af = __builtin_bit_cast(bf16x8,
          *reinterpret_cast<const uint4*>(&adjT[u & 1][aoffs]));
      const bf16x8 bv = __builtin_bit_cast(bf16x8,
          *reinterpret_cast<const uint4*>(&xlds[boffs + s * 32]));
      acc = __builtin_amdgcn_mfma_f32_16x16x32_bf16(af, bv, acc, 0, 0, 0);
    }
  }

  // write slots: lane holds D[n = w*16+lg*4+qq][slot = li]
  float* dst = aggX + ((size_t)(b * NN + ncol0)) * 72 + r * 8;
  if (li < 8) {
    #pragma unroll
    for (int qq = 0; qq < 4; ++qq) {
      const int n = w * 16 + lg * 4 + qq;
      dst[(size_t)n * 72 + li] = acc[qq];
    }
  }
}

// ---------------------------------------------------------------------------
// epilogue: out[b,n,o] = relu(bias[o] + aggX[o+r1]/deg + [r2!=r1] aggX[o+r2]/deg)
// ---------------------------------------------------------------------------
__global__ __launch_bounds__(256) void out_kernel(
    const float* __restrict__ aggX, const float* __restrict__ deg,
    const float* __restrict__ bias, float* __restrict__ out)
{
  const int gid = blockIdx.x * 256 + threadIdx.x;
  const int o = gid & 63;
  const int n = (gid >> 6) & 1023;
  const int b = gid >> 16;
  const float* cp = aggX + ((size_t)(b * NN + n)) * 72;

  const int r1 = (9 * o) >> 6;
  const int r2 = (9 * o + 8) >> 6;

  float v1 = cp[o + r1];
  if (r1 < 8) v1 /= (deg[(r1 * 4 + b) * NN + n] + EPSK);
  float acc = bias[o] + v1;
  if (r2 != r1) {
    float v2 = cp[o + r2];
    if (r2 < 8) v2 /= (deg[(r2 * 4 + b) * NN + n] + EPSK);
    acc += v2;
  }
  out[gid] = fmaxf(acc, 0.0f);
}

extern "C" void kernel_launch(void* const* d_in, const int* in_sizes, int n_in,
                              void* d_out, int out_size, void* d_ws, size_t ws_size,
                              hipStream_t stream) {
  const float* feat   = (const float*)d_in[0];
  const int*   adj    = (const int*)d_in[1];
  const float* weight = (const float*)d_in[2];
  const float* Wo     = (const float*)d_in[3];
  const float* wcmp   = (const float*)d_in[4];
  const float* bias   = (const float*)d_in[5];
  float* out = (float*)d_out;

  // ws layout: x~T (1 MiB bf16) | aggX (1.125 MiB f32) | deg (128 KiB f32)
  char* ws = (char*)d_ws;
  unsigned short* xT = (unsigned short*)(ws);
  float* aggX = (float*)(ws + 1048576u);
  float* deg  = (float*)(ws + 1048576u + 1179648u);

  prep_kernel<<<dim3(288), dim3(256), 0, stream>>>(feat, weight, Wo, wcmp, xT, aggX, deg);
  agg_kernel<<<dim3(512), dim3(256), 0, stream>>>(adj, xT, aggX, deg);
  out_kernel<<<dim3(1024), dim3(256), 0, stream>>>(aggX, deg, bias, out);
}